// Round 1
// baseline (352.662 us; speedup 1.0000x reference)
//
#include <hip/hip_runtime.h>
#include <stdint.h>

typedef short s16x8 __attribute__((ext_vector_type(8)));
typedef short s16x4 __attribute__((ext_vector_type(4)));
typedef float f32x4 __attribute__((ext_vector_type(4)));

#define MFMA16(a, b, c) __builtin_amdgcn_mfma_f32_16x16x32_bf16(a, b, c, 0, 0, 0)

__device__ __forceinline__ short f2bf(float f) {
  uint32_t u = __builtin_bit_cast(uint32_t, f);
  u += 0x7FFFu + ((u >> 16) & 1u);   // round-to-nearest-even
  return (short)(u >> 16);
}

// ---------------------------------------------------------------------------
// Weight pre-pack: bf16, MFMA B-fragment order. k = ks*32 + (lane>>4)*8 + e,
// n = ct*16 + (lane&15).  frag ids:
//   W0  (film0, K padded 49->64): frag = ct*2 + ks                (16 frags)
//   GB  (gamma/beta, 3 layers):   frag = 16 + l*32 + gb*16 + ct*2 + ks (96)
//   WH  (filmh, 2 layers):        frag = 112 + i*32 + ct*4 + ks   (64)
//   D1  (decW1):                  frag = 176 + ct*4 + ks          (16)
// total 192 frags * 512 elems = 98304 bf16 = 192 KiB in d_ws.
// feat layout: cols 0..47 = grids (gt0,gt1,gt2,gr0,gr1,gr2), col48 = rho,
// cols 49..63 = zero.  So W0 k<48 -> din 1+k, k==48 -> din 0, else 0.
// ---------------------------------------------------------------------------
__global__ void pack_w(const float* __restrict__ w0, const float* __restrict__ wh,
                       const float* __restrict__ gw, const float* __restrict__ bw,
                       const float* __restrict__ d1, short* __restrict__ out) {
  int idx = blockIdx.x * 512 + threadIdx.x;
  if (idx >= 98304) return;
  int f = idx >> 9;
  int r = idx & 511;
  int lane = r >> 3, e = r & 7;
  int kk = ((lane >> 4) << 3) + e;   // k within 32-slice
  int nn = lane & 15;
  float v;
  if (f < 16) {                       // W0
    int ct = f >> 1, ks = f & 1;
    int k = ks * 32 + kk, n = ct * 16 + nn;
    if (k < 48) v = w0[(1 + k) * 128 + n];
    else if (k == 48) v = w0[n];
    else v = 0.f;
  } else if (f < 112) {               // GB
    int f2 = f - 16;
    int ks = f2 & 1, ct = (f2 >> 1) & 7, gb = (f2 >> 4) & 1, l = f2 >> 5;
    int k = ks * 32 + kk, n = ct * 16 + nn;
    const float* Wp = gb ? bw : gw;
    v = Wp[(l * 64 + k) * 128 + n];
  } else if (f < 176) {               // WH
    int f2 = f - 112;
    int ks = f2 & 3, ct = (f2 >> 2) & 7, i = f2 >> 5;
    int k = ks * 32 + kk, n = ct * 16 + nn;
    v = wh[(i * 128 + k) * 128 + n];
  } else {                            // D1
    int f2 = f - 176;
    int ks = f2 & 3, ct = f2 >> 2;
    int k = ks * 32 + kk, n = ct * 16 + nn;
    v = d1[k * 64 + n];
  }
  out[idx] = f2bf(v);
}

// ---------------------------------------------------------------------------
// Main fused kernel. 512 threads (8 waves), 128 rows/block.
// Wave w owns output cols [w*16, w*16+16) for all 128-wide layers.
// LDS (64 KiB): feat[128][64] bf16 | cf[128][64] bf16 | x[128][128] bf16,
// all XOR-swizzled byte ^= (row&7)<<4 (G4 fix for stride-128B b128 reads).
// Residual x kept in f32 registers (xr[8][4]); LDS bf16 copy feeds MFMA only.
// ---------------------------------------------------------------------------
__global__ __launch_bounds__(512) void ngc_main(
    const float* __restrict__ coords, const float* __restrict__ angles,
    const float* __restrict__ rho, const float* __restrict__ rho_n,
    const float* __restrict__ cf, const float* __restrict__ ts,
    const float* __restrict__ gt0, const float* __restrict__ gr0,
    const float* __restrict__ gt1, const float* __restrict__ gr1,
    const float* __restrict__ gt2, const float* __restrict__ gr2,
    const float* __restrict__ f0b, const float* __restrict__ fhb,
    const float* __restrict__ gab, const float* __restrict__ beb,
    const float* __restrict__ d1b, const float* __restrict__ d2w,
    const float* __restrict__ d2b, const short* __restrict__ pw,
    float* __restrict__ out, int n) {
  __shared__ __align__(16) char smem[64 * 1024];
  char* featB = smem;                // 16 KiB
  char* cfB   = smem + 16 * 1024;    // 16 KiB
  char* xB    = smem + 32 * 1024;    // 32 KiB
  float* red  = (float*)smem;        // decoder partials, overlays feat

  const int tid = threadIdx.x;
  const int lane = tid & 63;
  const int w = tid >> 6;
  const int g16 = lane >> 4;
  const int l15 = lane & 15;
  const int row0 = blockIdx.x * 128;
  const int col = w * 16 + l15;

  // ---- Phase 0a: curve_feats -> LDS bf16 (swizzled) -----------------------
#pragma unroll
  for (int it = 0; it < 4; ++it) {
    int f4i = tid + it * 512;        // 0..2047 = 128 rows * 16 float4
    int r = f4i >> 4, c4 = f4i & 15;
    int gr_ = row0 + r; gr_ = gr_ < n ? gr_ : n - 1;
    float4 v = ((const float4*)cf)[(size_t)gr_ * 16 + c4];
    s16x4 s = { f2bf(v.x), f2bf(v.y), f2bf(v.z), f2bf(v.w) };
    *(s16x4*)(cfB + ((r * 128 + c4 * 8) ^ ((r & 7) << 4))) = s;
  }

  // ---- Phase 0b: rho into feat col 48, zero cols 49..63 -------------------
  if (tid < 128) {
    int r = tid;
    int gr_ = row0 + r; gr_ = gr_ < n ? gr_ : n - 1;
    s16x8 a = { f2bf(rho[gr_]), 0, 0, 0, 0, 0, 0, 0 };
    s16x8 z = { 0, 0, 0, 0, 0, 0, 0, 0 };
    *(s16x8*)(featB + ((r * 128 + 96)  ^ ((r & 7) << 4))) = a;
    *(s16x8*)(featB + ((r * 128 + 112) ^ ((r & 7) << 4))) = z;
  }

  // ---- Phase 0c: bilinear gathers, 6 grids x 128 rows ---------------------
  for (int task = tid; task < 768; task += 512) {
    int r = task & 127, g = task >> 7;            // g wave-uniform
    int gr_ = row0 + r; gr_ = gr_ < n ? gr_ : n - 1;
    float u = (g < 3) ? angles[gr_] : rho_n[gr_];
    float vv = coords[gr_];
    int lvl = (g < 3) ? g : g - 3;
    const float* G = (g == 0) ? gt0 : (g == 1) ? gt1 : (g == 2) ? gt2
                   : (g == 3) ? gr0 : (g == 4) ? gr1 : gr2;
    int Wg = 128 << lvl;
    float x = u * (float)(Wg - 1), y = vv * (float)(Wg - 1);
    int ix = (int)x; ix = ix < 0 ? 0 : (ix > Wg - 2 ? Wg - 2 : ix);
    int iy = (int)y; iy = iy < 0 ? 0 : (iy > Wg - 2 ? Wg - 2 : iy);
    float wx = x - (float)ix, wy = y - (float)iy;
    const float4* p0 = (const float4*)(G + (size_t)(iy * Wg + ix) * 8);
    const float4* p1 = (const float4*)(G + (size_t)((iy + 1) * Wg + ix) * 8);
    float4 c00a = p0[0], c00b = p0[1], c01a = p0[2], c01b = p0[3];
    float4 c10a = p1[0], c10b = p1[1], c11a = p1[2], c11b = p1[3];
    float w00 = (1.f - wx) * (1.f - wy), w01 = wx * (1.f - wy);
    float w10 = (1.f - wx) * wy, w11 = wx * wy;
    s16x8 o;
    o[0] = f2bf(c00a.x * w00 + c01a.x * w01 + c10a.x * w10 + c11a.x * w11);
    o[1] = f2bf(c00a.y * w00 + c01a.y * w01 + c10a.y * w10 + c11a.y * w11);
    o[2] = f2bf(c00a.z * w00 + c01a.z * w01 + c10a.z * w10 + c11a.z * w11);
    o[3] = f2bf(c00a.w * w00 + c01a.w * w01 + c10a.w * w10 + c11a.w * w11);
    o[4] = f2bf(c00b.x * w00 + c01b.x * w01 + c10b.x * w10 + c11b.x * w11);
    o[5] = f2bf(c00b.y * w00 + c01b.y * w01 + c10b.y * w10 + c11b.y * w11);
    o[6] = f2bf(c00b.z * w00 + c01b.z * w01 + c10b.z * w10 + c11b.z * w11);
    o[7] = f2bf(c00b.w * w00 + c01b.w * w01 + c10b.w * w10 + c11b.w * w11);
    *(s16x8*)(featB + ((r * 128 + g * 16) ^ ((r & 7) << 4))) = o;
  }
  __syncthreads();

  // fragment loaders: k = ks*32 + g16*8 + e (same kappa as pack_w -> correct
  // regardless of HW K-order, since A and B use the identical mapping)
  auto ldA64 = [&](const char* base, int rg, int ks) -> s16x8 {
    int r = rg * 16 + l15;
    return *(const s16x8*)(base + ((r * 128 + ks * 64 + g16 * 16) ^ ((r & 7) << 4)));
  };
  auto ldX = [&](int rg, int ks) -> s16x8 {
    int r = rg * 16 + l15;
    return *(const s16x8*)(xB + ((r * 256 + ks * 64 + g16 * 16) ^ ((r & 7) << 4)));
  };
  auto ldw = [&](int frag) -> s16x8 { return ((const s16x8*)pw)[frag * 64 + lane]; };

  float xr[8][4];

  // ---- Layer 0: x = silu(g0*(feat@W0+b0)+be0) + type_sample ---------------
  {
    s16x8 bw0 = ldw(w * 2 + 0), bw1 = ldw(w * 2 + 1);
    s16x8 bg0 = ldw(16 + w * 2 + 0), bg1 = ldw(16 + w * 2 + 1);
    s16x8 bb0 = ldw(32 + w * 2 + 0), bb1 = ldw(32 + w * 2 + 1);
    float f0bv = f0b[col], gabv = gab[col], bebv = beb[col];
#pragma unroll
    for (int rg = 0; rg < 8; ++rg) {
      f32x4 t = {0.f, 0.f, 0.f, 0.f};
      t = MFMA16(ldA64(featB, rg, 0), bw0, t);
      t = MFMA16(ldA64(featB, rg, 1), bw1, t);
      f32x4 ga = {0.f, 0.f, 0.f, 0.f};
      ga = MFMA16(ldA64(cfB, rg, 0), bg0, ga);
      ga = MFMA16(ldA64(cfB, rg, 1), bg1, ga);
      f32x4 be = {0.f, 0.f, 0.f, 0.f};
      be = MFMA16(ldA64(cfB, rg, 0), bb0, be);
      be = MFMA16(ldA64(cfB, rg, 1), bb1, be);
#pragma unroll
      for (int rr = 0; rr < 4; ++rr) {
        int grow = row0 + rg * 16 + g16 * 4 + rr; grow = grow < n ? grow : n - 1;
        float tsv = ts[(size_t)grow * 128 + col];
        float z = (ga[rr] + gabv) * (t[rr] + f0bv) + (be[rr] + bebv);
        float sl = z * __builtin_amdgcn_rcpf(1.f + __expf(-z));
        xr[rg][rr] = sl + tsv;
      }
    }
  }
#pragma unroll
  for (int rg = 0; rg < 8; ++rg)
#pragma unroll
    for (int rr = 0; rr < 4; ++rr) {
      int r = rg * 16 + g16 * 4 + rr;
      *(short*)(xB + ((r * 256 + col * 2) ^ ((r & 7) << 4))) = f2bf(xr[rg][rr]);
    }
  __syncthreads();

  // ---- Residual FiLM blocks ----------------------------------------------
#pragma unroll
  for (int i = 0; i < 2; ++i) {
    s16x8 bh0 = ldw(112 + i * 32 + w * 4 + 0);
    s16x8 bh1 = ldw(112 + i * 32 + w * 4 + 1);
    s16x8 bh2 = ldw(112 + i * 32 + w * 4 + 2);
    s16x8 bh3 = ldw(112 + i * 32 + w * 4 + 3);
    s16x8 bg0 = ldw(16 + (i + 1) * 32 + w * 2 + 0);
    s16x8 bg1 = ldw(16 + (i + 1) * 32 + w * 2 + 1);
    s16x8 bb0 = ldw(16 + (i + 1) * 32 + 16 + w * 2 + 0);
    s16x8 bb1 = ldw(16 + (i + 1) * 32 + 16 + w * 2 + 1);
    float fhbv = fhb[i * 128 + col];
    float gabv = gab[(i + 1) * 128 + col];
    float bebv = beb[(i + 1) * 128 + col];
#pragma unroll
    for (int rg = 0; rg < 8; ++rg) {
      f32x4 t = {0.f, 0.f, 0.f, 0.f};
      t = MFMA16(ldX(rg, 0), bh0, t);
      t = MFMA16(ldX(rg, 1), bh1, t);
      t = MFMA16(ldX(rg, 2), bh2, t);
      t = MFMA16(ldX(rg, 3), bh3, t);
      f32x4 ga = {0.f, 0.f, 0.f, 0.f};
      ga = MFMA16(ldA64(cfB, rg, 0), bg0, ga);
      ga = MFMA16(ldA64(cfB, rg, 1), bg1, ga);
      f32x4 be = {0.f, 0.f, 0.f, 0.f};
      be = MFMA16(ldA64(cfB, rg, 0), bb0, be);
      be = MFMA16(ldA64(cfB, rg, 1), bb1, be);
#pragma unroll
      for (int rr = 0; rr < 4; ++rr) {
        float z = (ga[rr] + gabv) * (t[rr] + fhbv) + (be[rr] + bebv);
        xr[rg][rr] += z * __builtin_amdgcn_rcpf(1.f + __expf(-z));
      }
    }
    __syncthreads();   // all waves done reading xB
#pragma unroll
    for (int rg = 0; rg < 8; ++rg)
#pragma unroll
      for (int rr = 0; rr < 4; ++rr) {
        int r = rg * 16 + g16 * 4 + rr;
        *(short*)(xB + ((r * 256 + col * 2) ^ ((r & 7) << 4))) = f2bf(xr[rg][rr]);
      }
    __syncthreads();
  }

  // ---- Decoder: relu(x@W1+b1)@W2+b2 --------------------------------------
  {
    int ctd = w & 3, rbase = (w >> 2) * 4;
    int dcol = ctd * 16 + l15;
    s16x8 bd0 = ldw(176 + ctd * 4 + 0);
    s16x8 bd1 = ldw(176 + ctd * 4 + 1);
    s16x8 bd2 = ldw(176 + ctd * 4 + 2);
    s16x8 bd3 = ldw(176 + ctd * 4 + 3);
    float d1bv = d1b[dcol], w2v = d2w[dcol];
#pragma unroll
    for (int q = 0; q < 4; ++q) {
      int rg = rbase + q;
      f32x4 hh = {0.f, 0.f, 0.f, 0.f};
      hh = MFMA16(ldX(rg, 0), bd0, hh);
      hh = MFMA16(ldX(rg, 1), bd1, hh);
      hh = MFMA16(ldX(rg, 2), bd2, hh);
      hh = MFMA16(ldX(rg, 3), bd3, hh);
#pragma unroll
      for (int rr = 0; rr < 4; ++rr) {
        float h = fmaxf(hh[rr] + d1bv, 0.f) * w2v;
        h += __shfl_xor(h, 1);
        h += __shfl_xor(h, 2);
        h += __shfl_xor(h, 4);
        h += __shfl_xor(h, 8);
        if (l15 == 0) red[(rg * 16 + g16 * 4 + rr) * 4 + ctd] = h;
      }
    }
  }
  __syncthreads();
  if (tid < 128) {
    int grow = row0 + tid;
    if (grow < n)
      out[grow] = red[tid * 4 + 0] + red[tid * 4 + 1] + red[tid * 4 + 2] +
                  red[tid * 4 + 3] + d2b[0];
  }
}

extern "C" void kernel_launch(void* const* d_in, const int* in_sizes, int n_in,
                              void* d_out, int out_size, void* d_ws, size_t ws_size,
                              hipStream_t stream) {
  int n = in_sizes[0];
  short* pw = (short*)d_ws;   // needs 192 KiB
  pack_w<<<192, 512, 0, stream>>>(
      (const float*)d_in[12],  // film0_fcW
      (const float*)d_in[14],  // filmh_fcW
      (const float*)d_in[16],  // gammaW
      (const float*)d_in[18],  // betaW
      (const float*)d_in[20],  // decW1
      pw);
  int nb = (n + 127) / 128;
  ngc_main<<<nb, 512, 0, stream>>>(
      (const float*)d_in[0],   // coords
      (const float*)d_in[1],   // angles
      (const float*)d_in[2],   // rho
      (const float*)d_in[3],   // rho_n
      (const float*)d_in[4],   // curve_feats
      (const float*)d_in[5],   // type_sample
      (const float*)d_in[6],   // gt0
      (const float*)d_in[7],   // gr0   (dict order: gt l, then gr l)
      (const float*)d_in[8],   // gt1
      (const float*)d_in[9],   // gr1
      (const float*)d_in[10],  // gt2
      (const float*)d_in[11],  // gr2
      (const float*)d_in[13],  // film0_fcb
      (const float*)d_in[15],  // filmh_fcb
      (const float*)d_in[17],  // gammab
      (const float*)d_in[19],  // betab
      (const float*)d_in[21],  // decb1
      (const float*)d_in[22],  // decW2
      (const float*)d_in[23],  // decb2
      pw, (float*)d_out, n);
}